// Round 1
// baseline (219.975 us; speedup 1.0000x reference)
//
#include <hip/hip_runtime.h>
#include <math.h>

// TopKRouter: x[16384,2048] fp32, W[64,2048] fp32
// out: [0..32767] top2 indices (as float), [32768..65535] gates, [65536] aux
// Split-fp16 MFMA (3-term: xh*wh + xh*wl + xl*wh). r5 structure (coalesced
// x -> LDS frag-linear -> b128 reads) with TM=16 / grid=1024 for 4 blocks/CU.
// R1: lgkm-only barriers in the K-loop (keep global prefetches in flight
// across s_barrier -- hipcc's __syncthreads drains vmcnt(0) and killed the
// pipeline), x prefetch depth 2->4, vectorized prep.
#define NTOK 16384
#define DDIM 2048
#define NEXP 64
#define TM   16                 // tokens per block (1 MFMA M-tile)
#define NBLK (NTOK / TM)        // 1024 blocks -> 4 blocks/CU
#define NCH  32                 // K chunks of 64
#define NS   64                 // K32 MFMA steps total

typedef _Float16 half4v __attribute__((ext_vector_type(4)));
typedef _Float16 half8v __attribute__((ext_vector_type(8)));
typedef float    f32x4  __attribute__((ext_vector_type(4)));

#define MFMA16(a, b, c) __builtin_amdgcn_mfma_f32_16x16x32_f16((a), (b), (c), 0, 0, 0)

// W prep: fp32 -> (wh, wl) fp16 in MFMA-B fragment-linear layout (r5-verified):
// element (e,k): S=k>>5, nb=e>>4, nl=e&15, q=(k>>3)&3, j=k&7
// off = S*2048 + nb*512 + q*128 + nl*8 + j
// One thread per (e, 8 consecutive k): j=0..7 contiguous -> half8v stores.
__global__ __launch_bounds__(256) void prep_kernel(const float* __restrict__ W,
                                                   _Float16* __restrict__ Wh,
                                                   _Float16* __restrict__ Wl,
                                                   float* __restrict__ accg) {
    int idx = blockIdx.x * 256 + threadIdx.x;   // 64 blocks -> 16384 threads
    int e  = idx >> 8;                          // 0..63
    int k0 = (idx & 255) << 3;                  // 0..2040, multiple of 8
    const float* wp = W + (size_t)e * DDIM + k0;
    float4 w0 = *(const float4*)wp;
    float4 w1 = *(const float4*)(wp + 4);
    half8v h, l;
    h[0] = (_Float16)w0.x; l[0] = (_Float16)(w0.x - (float)h[0]);
    h[1] = (_Float16)w0.y; l[1] = (_Float16)(w0.y - (float)h[1]);
    h[2] = (_Float16)w0.z; l[2] = (_Float16)(w0.z - (float)h[2]);
    h[3] = (_Float16)w0.w; l[3] = (_Float16)(w0.w - (float)h[3]);
    h[4] = (_Float16)w1.x; l[4] = (_Float16)(w1.x - (float)h[4]);
    h[5] = (_Float16)w1.y; l[5] = (_Float16)(w1.y - (float)h[5]);
    h[6] = (_Float16)w1.z; l[6] = (_Float16)(w1.z - (float)h[6]);
    h[7] = (_Float16)w1.w; l[7] = (_Float16)(w1.w - (float)h[7]);
    // 8 consecutive k (8-aligned) share S and q; j runs 0..7 contiguously
    int S = k0 >> 5, nb = e >> 4, nl = e & 15, q = (k0 >> 3) & 3;
    size_t off = (size_t)S * 2048 + nb * 512 + q * 128 + nl * 8;
    *(half8v*)&Wh[off] = h;
    *(half8v*)&Wl[off] = l;
    if (idx < 128) accg[idx] = 0.0f;
}

__device__ inline void cvt_store(_Float16* __restrict__ Hp, _Float16* __restrict__ Lp,
                                 int off, float4 v) {
    half4v h, l;
    h.x = (_Float16)v.x; l.x = (_Float16)(v.x - (float)h.x);
    h.y = (_Float16)v.y; l.y = (_Float16)(v.y - (float)h.y);
    h.z = (_Float16)v.z; l.z = (_Float16)(v.z - (float)h.z);
    h.w = (_Float16)v.w; l.w = (_Float16)(v.w - (float)h.w);
    *(half4v*)&Hp[off] = h;
    *(half4v*)&Lp[off] = l;
}

__global__ __launch_bounds__(256, 4) void router_kernel(
    const float* __restrict__ x, const _Float16* __restrict__ Wh,
    const _Float16* __restrict__ Wl, float* __restrict__ accg,
    float* __restrict__ out)
{
    // A (x) fp16 frag-linear, double-buffered: 2 K32-steps x 64 lanes x 8 halfs
    __shared__ __align__(16) _Float16 Ah[2][1024];   // 4 KB
    __shared__ __align__(16) _Float16 Al[2][1024];   // 4 KB
    __shared__ float lgt[TM][NEXP + 1];              // 4.2 KB
    __shared__ float cnt[NEXP];

    const int tid  = threadIdx.x;
    const int lane = tid & 63;
    const int wv   = __builtin_amdgcn_readfirstlane(tid >> 6);  // expert block 0..3
    const int m0   = blockIdx.x * TM;

    if (tid < NEXP) cnt[tid] = 0.0f;

    // staging map: thread t -> x[tok][kk..kk+3], tok=t>>4 (0..15), kk=(t&15)*4
    const int tok0 = tid >> 4;
    const int kk0  = (tid & 15) * 4;
    const int s0   = kk0 >> 5, q0 = (kk0 >> 3) & 3, j00 = kk0 & 7;
    const int offA = (s0 * 64 + q0 * 16 + tok0) * 8 + j00;

    const float* gx = x + (size_t)(m0 + tok0) * DDIM + kk0;

    // W-frag pointers for this wave's 16 experts (frag-linear, L2-hot)
    const _Float16* whp = Wh + wv * 512 + lane * 8;
    const _Float16* wlp = Wl + wv * 512 + lane * 8;

    f32x4 acc = {0.f, 0.f, 0.f, 0.f};

    // prologue: prefetch x chunks 0..3 and W steps 0,1
    float4 stg[4];
    #pragma unroll
    for (int i = 0; i < 4; ++i) stg[i] = *(const float4*)(gx + i * 64);
    half8v wbh[2], wbl[2];
    #pragma unroll
    for (int s = 0; s < 2; ++s) {
        wbh[s] = *(const half8v*)(whp + (size_t)s * 2048);
        wbl[s] = *(const half8v*)(wlp + (size_t)s * 2048);
    }

    for (int ch = 0; ch < NCH; ++ch) {
        const int p = ch & 1;
        const int b = ch & 3;
        // stage chunk ch -> LDS buf p (fp16 split, frag-linear)
        cvt_store(&Ah[p][0], &Al[p][0], offA, stg[b]);
        // depth-4 x prefetch (wrap reload harmless)
        const int cf = (ch + 4 < NCH) ? ch + 4 : 0;
        stg[b] = *(const float4*)(gx + cf * 64);
        // lgkm-only barrier: ds_write (staging) must be visible to readers,
        // but global prefetches (private VGPR dests) may stay in flight.
        // __syncthreads() would drain vmcnt(0) and collapse the pipeline.
        asm volatile("s_waitcnt lgkmcnt(0)" ::: "memory");
        __builtin_amdgcn_s_barrier();
        #pragma unroll
        for (int s = 0; s < 2; ++s) {
            const int Sg  = ch * 2 + s;
            const int SgN = (Sg + 2) & (NS - 1);
            half8v ah = *(const half8v*)&Ah[p][(s * 64 + lane) * 8];
            half8v al = *(const half8v*)&Al[p][(s * 64 + lane) * 8];
            half8v bh = wbh[s], bl = wbl[s];
            // prefetch W step Sg+2 into this parity slot
            wbh[s] = *(const half8v*)(whp + (size_t)SgN * 2048);
            wbl[s] = *(const half8v*)(wlp + (size_t)SgN * 2048);
            acc = MFMA16(al, bh, acc);
            acc = MFMA16(ah, bl, acc);
            acc = MFMA16(ah, bh, acc);
        }
    }

    // ---- C layout: row m=(lane>>4)*4+r, col n=lane&15 (m89/r5-verified) ----
    {
        const int q  = lane >> 4;
        const int nl = lane & 15;
        #pragma unroll
        for (int r = 0; r < 4; ++r)
            lgt[q * 4 + r][wv * 16 + nl] = acc[r];
    }
    __syncthreads();

    // ---- softmax + top-2: 8 threads per token (16 tok x 8 = 128 thr) ----
    if (tid < 128) {
        const int m = tid >> 3;
        const int j = tid & 7;
        float l[8];
        #pragma unroll
        for (int i = 0; i < 8; ++i) l[i] = lgt[m][j * 8 + i];

        float mx = l[0];
        #pragma unroll
        for (int i = 1; i < 8; ++i) mx = fmaxf(mx, l[i]);
        #pragma unroll
        for (int off = 1; off < 8; off <<= 1) mx = fmaxf(mx, __shfl_xor(mx, off, 8));

        float ev[8];
        float zs = 0.f;
        float v1 = -INFINITY, v2 = -INFINITY;
        int i1 = 0, i2 = 0;
        #pragma unroll
        for (int i = 0; i < 8; ++i) {
            ev[i] = __expf(l[i] - mx);
            zs += ev[i];
            int e = j * 8 + i;
            if (l[i] > v1)      { v2 = v1; i2 = i1; v1 = l[i]; i1 = e; }
            else if (l[i] > v2) { v2 = l[i]; i2 = e; }
        }
        #pragma unroll
        for (int off = 1; off < 8; off <<= 1) zs += __shfl_xor(zs, off, 8);

        // merge top-2 across 8 lanes (value desc, index asc on ties = lax.top_k)
        #pragma unroll
        for (int off = 1; off < 8; off <<= 1) {
            float ov1 = __shfl_xor(v1, off, 8);
            int   oi1 = __shfl_xor(i1, off, 8);
            float ov2 = __shfl_xor(v2, off, 8);
            int   oi2 = __shfl_xor(i2, off, 8);
            bool afirst = (v1 > ov1) || (v1 == ov1 && i1 < oi1);
            if (afirst) {
                bool t = (v2 > ov1) || (v2 == ov1 && i2 < oi1);
                v2 = t ? v2 : ov1;
                i2 = t ? i2 : oi1;
            } else {
                bool t = (ov2 > v1) || (ov2 == v1 && oi2 < i1);
                v2 = t ? ov2 : v1;
                i2 = t ? oi2 : i1;
                v1 = ov1;
                i1 = oi1;
            }
        }

        const float invz = 1.0f / zs;
        if (j == 0) {
            float p1 = invz;                      // v1 == mx exactly
            float p2 = __expf(v2 - mx) * invz;
            float sden = p1 + p2 + 1e-9f;
            int tok = m0 + m;
            out[tok * 2 + 0] = (float)i1;
            out[tok * 2 + 1] = (float)i2;
            out[32768 + tok * 2 + 0] = p1 / sden;
            out[32768 + tok * 2 + 1] = p2 / sden;
            atomicAdd(&cnt[i1], 1.0f);
            atomicAdd(&cnt[i2], 1.0f);
        }

        // probs writeback (own slots only)
        #pragma unroll
        for (int i = 0; i < 8; ++i) lgt[m][j * 8 + i] = ev[i] * invz;
    }
    __syncthreads();

    // global accumulators (accg zeroed by prep each launch)
    if (tid < NEXP) {
        atomicAdd(&accg[tid], cnt[tid]);
    } else if (tid < 128) {
        int e = tid - 64;
        float s = 0.f;
        #pragma unroll
        for (int t = 0; t < TM; ++t) s += lgt[t][e];
        atomicAdd(&accg[64 + e], s);
    }
}

__global__ void finalize_kernel(const float* __restrict__ accg,
                                float* __restrict__ out)
{
    int t = threadIdx.x;   // 64 threads
    float c = accg[t];
    float p = accg[64 + t];
    float term = (c / (float)(NTOK * 2)) * (p / (float)NTOK);
    #pragma unroll
    for (int off = 1; off < 64; off <<= 1) term += __shfl_xor(term, off, 64);
    if (t == 0) out[65536] = 0.01f * (float)NEXP * term;
}

extern "C" void kernel_launch(void* const* d_in, const int* in_sizes, int n_in,
                              void* d_out, int out_size, void* d_ws, size_t ws_size,
                              hipStream_t stream) {
    const float* x = (const float*)d_in[0];   // [4,4096,2048]
    const float* W = (const float*)d_in[1];   // [64,2048]
    float* out  = (float*)d_out;              // 65537 floats
    float* accg = (float*)d_ws;               // 128 floats
    _Float16* Wh = (_Float16*)(accg + 128);   // 131072 halfs (256 KB)
    _Float16* Wl = Wh + (size_t)DDIM * NEXP;  // 131072 halfs (256 KB)

    prep_kernel<<<64, 256, 0, stream>>>(W, Wh, Wl, accg);
    router_kernel<<<NBLK, 256, 0, stream>>>(x, Wh, Wl, accg, out);
    finalize_kernel<<<1, 64, 0, stream>>>(accg, out);
}

// Round 2
// 212.519 us; speedup vs baseline: 1.0351x; 1.0351x over previous
//
#include <hip/hip_runtime.h>
#include <math.h>

// TopKRouter: x[16384,2048] fp32, W[64,2048] fp32
// out: [0..32767] top2 indices (as float), [32768..65535] gates, [65536] aux
// Split-fp16 MFMA (3-term: xh*wh + xh*wl + xl*wh). r5 structure (coalesced
// x -> LDS frag-linear -> b128 reads) with TM=16 / grid=1024 for 4 blocks/CU.
// R1: lgkm-only barriers in the K-loop.
// R2: rule-#20 fix -- R0/R1 had stg[b]/wb[s] runtime-indexed -> scratch spill
// (VGPR_Count=32 proved it); now hand-unrolled x4 with NAMED registers so the
// prefetch pipeline actually lives in VGPRs. W ring deepened to 4 slots
// (distance 2 chunks). LDS A-tile XOR-swizzled (g ^= (g>>4)&7, 16B granules):
// ds_write was 8-banks-per-wave (7.4M conflict cycles), now 4-slot minimum.
#define NTOK 16384
#define DDIM 2048
#define NEXP 64
#define TM   16                 // tokens per block (1 MFMA M-tile)
#define NBLK (NTOK / TM)        // 1024 blocks -> 4 blocks/CU
#define NCH  32                 // K chunks of 64
#define NS   64                 // K32 MFMA steps total

typedef _Float16 half4v __attribute__((ext_vector_type(4)));
typedef _Float16 half8v __attribute__((ext_vector_type(8)));
typedef float    f32x4  __attribute__((ext_vector_type(4)));

#define MFMA16(a, b, c) __builtin_amdgcn_mfma_f32_16x16x32_f16((a), (b), (c), 0, 0, 0)

// W prep: fp32 -> (wh, wl) fp16 in MFMA-B fragment-linear layout (r5-verified):
// element (e,k): S=k>>5, nb=e>>4, nl=e&15, q=(k>>3)&3, j=k&7
// off = S*2048 + nb*512 + q*128 + nl*8 + j   (GLOBAL layout: unswizzled)
__global__ __launch_bounds__(256) void prep_kernel(const float* __restrict__ W,
                                                   _Float16* __restrict__ Wh,
                                                   _Float16* __restrict__ Wl,
                                                   float* __restrict__ accg) {
    int idx = blockIdx.x * 256 + threadIdx.x;   // 64 blocks -> 16384 threads
    int e  = idx >> 8;                          // 0..63
    int k0 = (idx & 255) << 3;                  // 0..2040, multiple of 8
    const float* wp = W + (size_t)e * DDIM + k0;
    float4 w0 = *(const float4*)wp;
    float4 w1 = *(const float4*)(wp + 4);
    half8v h, l;
    h[0] = (_Float16)w0.x; l[0] = (_Float16)(w0.x - (float)h[0]);
    h[1] = (_Float16)w0.y; l[1] = (_Float16)(w0.y - (float)h[1]);
    h[2] = (_Float16)w0.z; l[2] = (_Float16)(w0.z - (float)h[2]);
    h[3] = (_Float16)w0.w; l[3] = (_Float16)(w0.w - (float)h[3]);
    h[4] = (_Float16)w1.x; l[4] = (_Float16)(w1.x - (float)h[4]);
    h[5] = (_Float16)w1.y; l[5] = (_Float16)(w1.y - (float)h[5]);
    h[6] = (_Float16)w1.z; l[6] = (_Float16)(w1.z - (float)h[6]);
    h[7] = (_Float16)w1.w; l[7] = (_Float16)(w1.w - (float)h[7]);
    int S = k0 >> 5, nb = e >> 4, nl = e & 15, q = (k0 >> 3) & 3;
    size_t off = (size_t)S * 2048 + nb * 512 + q * 128 + nl * 8;
    *(half8v*)&Wh[off] = h;
    *(half8v*)&Wl[off] = l;
    if (idx < 128) accg[idx] = 0.0f;
}

__device__ inline void cvt_store(_Float16* __restrict__ Hp, _Float16* __restrict__ Lp,
                                 int off, float4 v) {
    half4v h, l;
    h.x = (_Float16)v.x; l.x = (_Float16)(v.x - (float)h.x);
    h.y = (_Float16)v.y; l.y = (_Float16)(v.y - (float)h.y);
    h.z = (_Float16)v.z; l.z = (_Float16)(v.z - (float)h.z);
    h.w = (_Float16)v.w; l.w = (_Float16)(v.w - (float)h.w);
    *(half4v*)&Hp[off] = h;
    *(half4v*)&Lp[off] = l;
}

__global__ __launch_bounds__(256, 4) void router_kernel(
    const float* __restrict__ x, const _Float16* __restrict__ Wh,
    const _Float16* __restrict__ Wl, float* __restrict__ accg,
    float* __restrict__ out)
{
    // A (x) fp16 frag-linear (XOR-swizzled, 16B granules), double-buffered
    __shared__ __align__(16) _Float16 Ah[2][1024];   // 4 KB
    __shared__ __align__(16) _Float16 Al[2][1024];   // 4 KB
    __shared__ float lgt[TM][NEXP + 1];              // 4.2 KB
    __shared__ float cnt[NEXP];

    const int tid  = threadIdx.x;
    const int lane = tid & 63;
    const int wv   = __builtin_amdgcn_readfirstlane(tid >> 6);  // expert block 0..3
    const int m0   = blockIdx.x * TM;

    if (tid < NEXP) cnt[tid] = 0.0f;

    // staging map: thread t -> x[tok][kk..kk+3], tok=t>>4 (0..15), kk=(t&15)*4
    const int tok0 = tid >> 4;
    const int kk0  = (tid & 15) * 4;
    const int s0   = kk0 >> 5, q0 = (kk0 >> 3) & 3, j00 = kk0 & 7;
    // group index g in [0,128); swizzle g ^= (g>>4)&7 (applied on BOTH sides)
    const int gW   = s0 * 64 + q0 * 16 + tok0;
    const int offA = ((gW ^ ((gW >> 4) & 7)) << 3) + j00;

    // read groups for steps s=0,1 (same swizzle)
    const int gr0 = lane;
    const int gr1 = 64 + lane;
    const int rdoff0 = (gr0 ^ ((gr0 >> 4) & 7)) << 3;
    const int rdoff1 = (gr1 ^ ((gr1 >> 4) & 7)) << 3;

    const float* gx = x + (size_t)(m0 + tok0) * DDIM + kk0;

    // W-frag pointers for this wave's 16 experts (frag-linear, L2-hot)
    const _Float16* whp = Wh + wv * 512 + lane * 8;
    const _Float16* wlp = Wl + wv * 512 + lane * 8;

    f32x4 acc = {0.f, 0.f, 0.f, 0.f};

    // prologue: prefetch x chunks 0..3 (NAMED regs) and W steps 0..3
    float4 stg0 = *(const float4*)(gx);
    float4 stg1 = *(const float4*)(gx + 64);
    float4 stg2 = *(const float4*)(gx + 128);
    float4 stg3 = *(const float4*)(gx + 192);
    half8v wh0 = *(const half8v*)(whp);
    half8v wh1 = *(const half8v*)(whp + 2048);
    half8v wh2 = *(const half8v*)(whp + 4096);
    half8v wh3 = *(const half8v*)(whp + 6144);
    half8v wl0 = *(const half8v*)(wlp);
    half8v wl1 = *(const half8v*)(wlp + 2048);
    half8v wl2 = *(const half8v*)(wlp + 4096);
    half8v wl3 = *(const half8v*)(wlp + 6144);

    // One chunk: stage STG -> LDS[P]; prefetch x(ch+4) into STG; lgkm-only
    // barrier (global prefetches stay in flight across s_barrier); 2 K32
    // steps consuming W slots (WA=slot Sg&3==2ch&3, WB=slot (2ch+1)&3),
    // each prefetching step Sg+4 back into its own slot.
#define CHUNK(ch, STG, P, WHA, WLA, WHB, WLB)                               \
    {                                                                        \
        cvt_store(&Ah[P][0], &Al[P][0], offA, STG);                          \
        const int cf = ((ch) + 4 < NCH) ? (ch) + 4 : 0;                      \
        STG = *(const float4*)(gx + cf * 64);                                \
        asm volatile("s_waitcnt lgkmcnt(0)" ::: "memory");                   \
        __builtin_amdgcn_s_barrier();                                        \
        {   /* step Sg = 2*ch */                                             \
            half8v ah = *(const half8v*)&Ah[P][rdoff0];                      \
            half8v al = *(const half8v*)&Al[P][rdoff0];                      \
            half8v bh = WHA, bl = WLA;                                       \
            const int SgN = (2 * (ch) + 4) & (NS - 1);                       \
            WHA = *(const half8v*)(whp + (size_t)SgN * 2048);                \
            WLA = *(const half8v*)(wlp + (size_t)SgN * 2048);                \
            acc = MFMA16(al, bh, acc);                                       \
            acc = MFMA16(ah, bl, acc);                                       \
            acc = MFMA16(ah, bh, acc);                                       \
        }                                                                    \
        {   /* step Sg = 2*ch+1 */                                           \
            half8v ah = *(const half8v*)&Ah[P][rdoff1];                      \
            half8v al = *(const half8v*)&Al[P][rdoff1];                      \
            half8v bh = WHB, bl = WLB;                                       \
            const int SgN = (2 * (ch) + 5) & (NS - 1);                       \
            WHB = *(const half8v*)(whp + (size_t)SgN * 2048);                \
            WLB = *(const half8v*)(wlp + (size_t)SgN * 2048);                \
            acc = MFMA16(al, bh, acc);                                       \
            acc = MFMA16(ah, bl, acc);                                       \
            acc = MFMA16(ah, bh, acc);                                       \
        }                                                                    \
    }

    for (int cb = 0; cb < NCH; cb += 4) {
        CHUNK(cb + 0, stg0, 0, wh0, wl0, wh1, wl1);
        CHUNK(cb + 1, stg1, 1, wh2, wl2, wh3, wl3);
        CHUNK(cb + 2, stg2, 0, wh0, wl0, wh1, wl1);
        CHUNK(cb + 3, stg3, 1, wh2, wl2, wh3, wl3);
    }
#undef CHUNK

    // ---- C layout: row m=(lane>>4)*4+r, col n=lane&15 (m89/r5-verified) ----
    {
        const int q  = lane >> 4;
        const int nl = lane & 15;
        #pragma unroll
        for (int r = 0; r < 4; ++r)
            lgt[q * 4 + r][wv * 16 + nl] = acc[r];
    }
    __syncthreads();

    // ---- softmax + top-2: 8 threads per token (16 tok x 8 = 128 thr) ----
    if (tid < 128) {
        const int m = tid >> 3;
        const int j = tid & 7;
        float l[8];
        #pragma unroll
        for (int i = 0; i < 8; ++i) l[i] = lgt[m][j * 8 + i];

        float mx = l[0];
        #pragma unroll
        for (int i = 1; i < 8; ++i) mx = fmaxf(mx, l[i]);
        #pragma unroll
        for (int off = 1; off < 8; off <<= 1) mx = fmaxf(mx, __shfl_xor(mx, off, 8));

        float ev[8];
        float zs = 0.f;
        float v1 = -INFINITY, v2 = -INFINITY;
        int i1 = 0, i2 = 0;
        #pragma unroll
        for (int i = 0; i < 8; ++i) {
            ev[i] = __expf(l[i] - mx);
            zs += ev[i];
            int e = j * 8 + i;
            if (l[i] > v1)      { v2 = v1; i2 = i1; v1 = l[i]; i1 = e; }
            else if (l[i] > v2) { v2 = l[i]; i2 = e; }
        }
        #pragma unroll
        for (int off = 1; off < 8; off <<= 1) zs += __shfl_xor(zs, off, 8);

        // merge top-2 across 8 lanes (value desc, index asc on ties = lax.top_k)
        #pragma unroll
        for (int off = 1; off < 8; off <<= 1) {
            float ov1 = __shfl_xor(v1, off, 8);
            int   oi1 = __shfl_xor(i1, off, 8);
            float ov2 = __shfl_xor(v2, off, 8);
            int   oi2 = __shfl_xor(i2, off, 8);
            bool afirst = (v1 > ov1) || (v1 == ov1 && i1 < oi1);
            if (afirst) {
                bool t = (v2 > ov1) || (v2 == ov1 && i2 < oi1);
                v2 = t ? v2 : ov1;
                i2 = t ? i2 : oi1;
            } else {
                bool t = (ov2 > v1) || (ov2 == v1 && oi2 < i1);
                v2 = t ? ov2 : v1;
                i2 = t ? oi2 : i1;
                v1 = ov1;
                i1 = oi1;
            }
        }

        const float invz = 1.0f / zs;
        if (j == 0) {
            float p1 = invz;                      // v1 == mx exactly
            float p2 = __expf(v2 - mx) * invz;
            float sden = p1 + p2 + 1e-9f;
            int tok = m0 + m;
            out[tok * 2 + 0] = (float)i1;
            out[tok * 2 + 1] = (float)i2;
            out[32768 + tok * 2 + 0] = p1 / sden;
            out[32768 + tok * 2 + 1] = p2 / sden;
            atomicAdd(&cnt[i1], 1.0f);
            atomicAdd(&cnt[i2], 1.0f);
        }

        // probs writeback (own slots only)
        #pragma unroll
        for (int i = 0; i < 8; ++i) lgt[m][j * 8 + i] = ev[i] * invz;
    }
    __syncthreads();

    // global accumulators (accg zeroed by prep each launch)
    if (tid < NEXP) {
        atomicAdd(&accg[tid], cnt[tid]);
    } else if (tid < 128) {
        int e = tid - 64;
        float s = 0.f;
        #pragma unroll
        for (int t = 0; t < TM; ++t) s += lgt[t][e];
        atomicAdd(&accg[64 + e], s);
    }
}

__global__ void finalize_kernel(const float* __restrict__ accg,
                                float* __restrict__ out)
{
    int t = threadIdx.x;   // 64 threads
    float c = accg[t];
    float p = accg[64 + t];
    float term = (c / (float)(NTOK * 2)) * (p / (float)NTOK);
    #pragma unroll
    for (int off = 1; off < 64; off <<= 1) term += __shfl_xor(term, off, 64);
    if (t == 0) out[65536] = 0.01f * (float)NEXP * term;
}

extern "C" void kernel_launch(void* const* d_in, const int* in_sizes, int n_in,
                              void* d_out, int out_size, void* d_ws, size_t ws_size,
                              hipStream_t stream) {
    const float* x = (const float*)d_in[0];   // [4,4096,2048]
    const float* W = (const float*)d_in[1];   // [64,2048]
    float* out  = (float*)d_out;              // 65537 floats
    float* accg = (float*)d_ws;               // 128 floats
    _Float16* Wh = (_Float16*)(accg + 128);   // 131072 halfs (256 KB)
    _Float16* Wl = Wh + (size_t)DDIM * NEXP;  // 131072 halfs (256 KB)

    prep_kernel<<<64, 256, 0, stream>>>(W, Wh, Wl, accg);
    router_kernel<<<NBLK, 256, 0, stream>>>(x, Wh, Wl, accg, out);
    finalize_kernel<<<1, 64, 0, stream>>>(accg, out);
}